// Round 1
// baseline (5243.193 us; speedup 1.0000x reference)
//
#include <hip/hip_runtime.h>

#define TPB 256

// ---- mean-VFE: x[n,c] = sum_p voxels[n,p,c] / max(nump[n],1), p=0..4, c=0..3
__global__ void vfe_kernel(const float* __restrict__ voxels,
                           const int* __restrict__ nump,
                           float* __restrict__ x, int N) {
    int i = blockIdx.x * blockDim.x + threadIdx.x;
    if (i >= N * 4) return;
    int n = i >> 2, c = i & 3;
    const float* v = voxels + (long)n * 20 + c;
    float s = v[0] + v[4] + v[8] + v[12] + v[16];
    x[i] = s / fmaxf((float)nump[n], 1.0f);
}

// ---- gather -> per-offset GEMM row -> scatter-add (one thread per (pair, out_chan))
__global__ void sconv_kernel(const float* __restrict__ feats,
                             const float* __restrict__ w,
                             const int* __restrict__ rb_in,
                             const int* __restrict__ rb_out,
                             float* __restrict__ out,
                             int KP, int P, int ci, int co, int n_in_rows) {
    long t = (long)blockIdx.x * blockDim.x + threadIdx.x;
    long pair = t / co;
    int  o    = (int)(t % co);
    if (pair >= (long)KP) return;
    int in_idx = rb_in[pair];
    if (in_idx == n_in_rows) return;           // sentinel (padded entry)
    int out_idx = rb_out[pair];
    int k = (int)(pair / P);
    const float* f  = feats + (long)in_idx * ci;
    const float* wk = w + (long)k * ci * co + o;
    float acc = 0.f;
    for (int c = 0; c < ci; ++c)
        acc = fmaf(f[c], wk[(long)c * co], acc);
    atomicAdd(out + (long)out_idx * co + o, acc);
}

// ---- eval-mode BatchNorm1d(eps=1e-3) + ReLU, in place
__global__ void bnrelu_kernel(float* __restrict__ x,
                              const float* __restrict__ bn,
                              long total, int co) {
    long t = (long)blockIdx.x * blockDim.x + threadIdx.x;
    if (t >= total) return;
    int o = (int)(t % co);
    float g = bn[o], b = bn[co + o], m = bn[2 * co + o], v = bn[3 * co + o];
    float y = (x[t] - m) * rsqrtf(v + 1e-3f) * g + b;
    x[t] = fmaxf(y, 0.f);
}

// ---- per-batch global max pool (values are >=0 post-ReLU; out pre-zeroed)
__global__ void segmax_kernel(const float* __restrict__ x,
                              const int* __restrict__ bidx,
                              float* __restrict__ out, long total, int co) {
    long t = (long)blockIdx.x * blockDim.x + threadIdx.x;
    if (t >= total) return;
    long r = t / co;
    int  o = (int)(t % co);
    float v = x[t];
    atomicMax((int*)out + (long)bidx[r] * co + o, __float_as_int(v));
}

extern "C" void kernel_launch(void* const* d_in, const int* in_sizes, int n_in,
                              void* d_out, int out_size, void* d_ws, size_t ws_size,
                              hipStream_t stream) {
    (void)n_in; (void)ws_size;
    const float* voxels = (const float*)d_in[24];
    const int*   nump   = (const int*)d_in[25];
    const int N  = in_sizes[25];
    const int n2 = in_sizes[30] / 27;   // SubM pad width == site count
    const int n3 = in_sizes[34] / 27;
    const int n4 = in_sizes[38] / 27;
    const int n5 = in_sizes[42];        // batch_idx length

    struct L { int wi, rb, K, ci, co, nin, nout; };
    const L layers[12] = {
        {0,  26, 27,  4,  16, N,  N },   // conv_input (subm1)
        {1,  26, 27, 16,  16, N,  N },   // conv1      (subm1)
        {2,  28, 27, 16,  32, N,  n2},   // conv2 down (down2)
        {3,  30, 27, 32,  32, n2, n2},   // subm2
        {4,  30, 27, 32,  32, n2, n2},   // subm2
        {5,  32, 27, 32,  64, n2, n3},   // conv3 down (down3)
        {6,  34, 27, 64,  64, n3, n3},   // subm3
        {7,  34, 27, 64,  64, n3, n3},   // subm3
        {8,  36, 27, 64,  64, n3, n4},   // conv4 down (down4)
        {9,  38, 27, 64,  64, n4, n4},   // subm4
        {10, 38, 27, 64,  64, n4, n4},   // subm4
        {11, 40,  3, 64, 128, n4, n5},   // conv_out
    };

    // two ping-pong buffers in workspace, each big enough for any layer output
    size_t need = (size_t)N * 4;
    for (int i = 0; i < 12; ++i) {
        size_t s = (size_t)layers[i].nout * layers[i].co;
        if (s > need) need = s;
    }
    size_t stride_b = ((need * sizeof(float)) + 255) & ~(size_t)255;
    float* bufA = (float*)d_ws;
    float* bufB = (float*)((char*)d_ws + stride_b);

    // VFE
    {
        long tot = (long)N * 4;
        vfe_kernel<<<dim3((unsigned)((tot + TPB - 1) / TPB)), dim3(TPB), 0, stream>>>(
            voxels, nump, bufA, N);
    }

    float* cur = bufA;
    float* nxt = bufB;
    for (int i = 0; i < 12; ++i) {
        const L& l = layers[i];
        const float* w  = (const float*)d_in[2 * l.wi];
        const float* bn = (const float*)d_in[2 * l.wi + 1];
        const int* rin  = (const int*)d_in[l.rb];
        const int* rout = (const int*)d_in[l.rb + 1];
        int P  = in_sizes[l.rb] / l.K;
        int KP = l.K * P;

        hipMemsetAsync(nxt, 0, (size_t)l.nout * l.co * sizeof(float), stream);

        long tot = (long)KP * l.co;
        sconv_kernel<<<dim3((unsigned)((tot + TPB - 1) / TPB)), dim3(TPB), 0, stream>>>(
            cur, w, rin, rout, nxt, KP, P, l.ci, l.co, l.nin);

        long tot2 = (long)l.nout * l.co;
        bnrelu_kernel<<<dim3((unsigned)((tot2 + TPB - 1) / TPB)), dim3(TPB), 0, stream>>>(
            nxt, bn, tot2, l.co);

        float* tmp = cur; cur = nxt; nxt = tmp;
    }

    // segment max -> d_out (zero-init; post-ReLU values are non-negative)
    hipMemsetAsync(d_out, 0, (size_t)out_size * sizeof(float), stream);
    const int* bidx = (const int*)d_in[42];
    long tot = (long)n5 * 128;
    segmax_kernel<<<dim3((unsigned)((tot + TPB - 1) / TPB)), dim3(TPB), 0, stream>>>(
        cur, bidx, (float*)d_out, tot, 128);
}

// Round 2
// 1217.810 us; speedup vs baseline: 4.3054x; 4.3054x over previous
//
#include <hip/hip_runtime.h>

#define TPB 256

// ---- mean-VFE: x[n,c] = sum_p voxels[n,p,c] / max(nump[n],1), p=0..4, c=0..3
__global__ void vfe_kernel(const float* __restrict__ voxels,
                           const int* __restrict__ nump,
                           float* __restrict__ x, int N) {
    int i = blockIdx.x * blockDim.x + threadIdx.x;
    if (i >= N * 4) return;
    int n = i >> 2, c = i & 3;
    const float* v = voxels + (long)n * 20 + c;
    float s = v[0] + v[4] + v[8] + v[12] + v[16];
    x[i] = s / fmaxf((float)nump[n], 1.0f);
}

// ---- invert rulebook: inv[out_row][k] = in_row (or -1)
// Within a tap k, output indices are unique -> plain stores, no atomics.
__global__ void inv_build_kernel(const int* __restrict__ rb_in,
                                 const int* __restrict__ rb_out,
                                 int* __restrict__ inv,
                                 int KP, int P, int K, int n_in) {
    int t = blockIdx.x * blockDim.x + threadIdx.x;
    if (t >= KP) return;
    int ii = rb_in[t];
    if (ii == n_in) return;                 // padded sentinel
    int k = t / P;
    inv[(long)rb_out[t] * K + k] = ii;
}

// ---- output-centric sparse conv + fused BN(eval)+ReLU
// Block: TP output rows x CO cols. Loop K taps: stage W_k + gathered A into
// LDS, register-accumulate. Epilogue: BN+ReLU, float4 store. No atomics.
template<int CI, int CO, int TP, int K>
__global__ __launch_bounds__(256)
void conv_kernel(const float* __restrict__ feats,
                 const float* __restrict__ w,    // [K][CI][CO]
                 const float* __restrict__ bn,   // [4][CO]
                 const int* __restrict__ inv,    // [n_out][K]
                 float* __restrict__ out,        // [n_out][CO]
                 int n_out) {
    constexpr int OG  = CO / 4;       // float4 col groups
    constexpr int PTH = 256 / OG;     // row-threads
    constexpr int PT  = TP / PTH;     // rows per thread
    constexpr int CIP = CI + 4;       // padded LDS stride (banks + alignment)

    __shared__ float sW[CI * CO];
    __shared__ float sA[TP * CIP];

    const int brow = blockIdx.x * TP;
    const int t  = threadIdx.x;
    const int og = t % OG;            // cols og*4 .. og*4+3
    const int pg = t / OG;            // row-thread id -> rows pg*PT .. pg*PT+PT-1

    float acc[PT][4];
    #pragma unroll
    for (int i = 0; i < PT; ++i)
        acc[i][0] = acc[i][1] = acc[i][2] = acc[i][3] = 0.f;

    for (int k = 0; k < K; ++k) {
        __syncthreads();
        // stage W_k (contiguous, coalesced float4)
        {
            const float4* src = (const float4*)(w + (long)k * CI * CO);
            #pragma unroll
            for (int i = t; i < CI * CO / 4; i += 256)
                ((float4*)sW)[i] = src[i];
        }
        // gather A rows via inverted rulebook (sentinel -> zeros)
        {
            constexpr int TR  = CI / 4;           // float4 threads per row
            constexpr int RPS = 256 / TR;         // rows per sweep
            #pragma unroll
            for (int s = 0; s < (TP + RPS - 1) / RPS; ++s) {
                int r = s * RPS + t / TR;
                int c = (t % TR) * 4;
                if (r < TP) {
                    int grow = brow + r;
                    int idx = (grow < n_out) ? inv[(long)grow * K + k] : -1;
                    float4 v = make_float4(0.f, 0.f, 0.f, 0.f);
                    if (idx >= 0)
                        v = *(const float4*)(feats + (long)idx * CI + c);
                    *(float4*)(sA + r * CIP + c) = v;
                }
            }
        }
        __syncthreads();
        // register-tile GEMM: acc[p][0..3] += A[p][kk] * W[kk][og*4..+3]
        #pragma unroll 4
        for (int kk = 0; kk < CI; ++kk) {
            float4 wv = *(const float4*)(sW + kk * CO + og * 4);
            #pragma unroll
            for (int i = 0; i < PT; ++i) {
                float a = sA[(pg * PT + i) * CIP + kk];
                acc[i][0] = fmaf(a, wv.x, acc[i][0]);
                acc[i][1] = fmaf(a, wv.y, acc[i][1]);
                acc[i][2] = fmaf(a, wv.z, acc[i][2]);
                acc[i][3] = fmaf(a, wv.w, acc[i][3]);
            }
        }
    }

    // fused eval-BN(eps=1e-3) + ReLU, then store
    float4 g = *(const float4*)(bn + og * 4);
    float4 b = *(const float4*)(bn + CO + og * 4);
    float4 m = *(const float4*)(bn + 2 * CO + og * 4);
    float4 v = *(const float4*)(bn + 3 * CO + og * 4);
    float s0 = rsqrtf(v.x + 1e-3f) * g.x;
    float s1 = rsqrtf(v.y + 1e-3f) * g.y;
    float s2 = rsqrtf(v.z + 1e-3f) * g.z;
    float s3 = rsqrtf(v.w + 1e-3f) * g.w;
    #pragma unroll
    for (int i = 0; i < PT; ++i) {
        int grow = brow + pg * PT + i;
        if (grow < n_out) {
            float4 o;
            o.x = fmaxf(fmaf(acc[i][0] - m.x, s0, b.x), 0.f);
            o.y = fmaxf(fmaf(acc[i][1] - m.y, s1, b.y), 0.f);
            o.z = fmaxf(fmaf(acc[i][2] - m.z, s2, b.z), 0.f);
            o.w = fmaxf(fmaf(acc[i][3] - m.w, s3, b.w), 0.f);
            *(float4*)(out + (long)grow * CO + og * 4) = o;
        }
    }
}

// ---- per-batch global max pool (post-ReLU values >= 0; out pre-zeroed)
__global__ void segmax_kernel(const float* __restrict__ x,
                              const int* __restrict__ bidx,
                              float* __restrict__ out, long total, int co) {
    long t = (long)blockIdx.x * blockDim.x + threadIdx.x;
    if (t >= total) return;
    long r = t / co;
    int  o = (int)(t % co);
    atomicMax((int*)out + (long)bidx[r] * co + o, __float_as_int(x[t]));
}

extern "C" void kernel_launch(void* const* d_in, const int* in_sizes, int n_in,
                              void* d_out, int out_size, void* d_ws, size_t ws_size,
                              hipStream_t stream) {
    (void)n_in; (void)ws_size;
    const float* voxels = (const float*)d_in[24];
    const int*   nump   = (const int*)d_in[25];
    const int N  = in_sizes[25];
    const int n2 = in_sizes[30] / 27;   // SubM pad width == site count
    const int n3 = in_sizes[34] / 27;
    const int n4 = in_sizes[38] / 27;
    const int n5 = in_sizes[42];        // batch_idx length

    struct L { int wi, rb, K, ci, co, nin, nout; };
    const L layers[12] = {
        {0,  26, 27,  4,  16, N,  N },   // conv_input (subm1)
        {1,  26, 27, 16,  16, N,  N },   // conv1      (subm1)
        {2,  28, 27, 16,  32, N,  n2},   // conv2 down (down2)
        {3,  30, 27, 32,  32, n2, n2},   // subm2
        {4,  30, 27, 32,  32, n2, n2},   // subm2
        {5,  32, 27, 32,  64, n2, n3},   // conv3 down (down3)
        {6,  34, 27, 64,  64, n3, n3},   // subm3
        {7,  34, 27, 64,  64, n3, n3},   // subm3
        {8,  36, 27, 64,  64, n3, n4},   // conv4 down (down4)
        {9,  38, 27, 64,  64, n4, n4},   // subm4
        {10, 38, 27, 64,  64, n4, n4},   // subm4
        {11, 40,  3, 64, 128, n4, n5},   // conv_out
    };

    // workspace layout: inv table | feats bufA | feats bufB
    size_t inv_elems = 0, feat_elems = (size_t)N * 4;
    for (int i = 0; i < 12; ++i) {
        size_t ie = (size_t)layers[i].nout * layers[i].K;
        size_t fe = (size_t)layers[i].nout * layers[i].co;
        if (ie > inv_elems)  inv_elems  = ie;
        if (fe > feat_elems) feat_elems = fe;
    }
    size_t inv_b  = (inv_elems  * sizeof(int)   + 255) & ~(size_t)255;
    size_t feat_b = (feat_elems * sizeof(float) + 255) & ~(size_t)255;
    int*   inv  = (int*)d_ws;
    float* bufA = (float*)((char*)d_ws + inv_b);
    float* bufB = (float*)((char*)d_ws + inv_b + feat_b);

    // VFE
    {
        long tot = (long)N * 4;
        vfe_kernel<<<dim3((unsigned)((tot + TPB - 1) / TPB)), dim3(TPB), 0, stream>>>(
            voxels, nump, bufA, N);
    }

    float* cur = bufA;
    float* nxt = bufB;
    int prev_rb = -1;
    for (int i = 0; i < 12; ++i) {
        const L& l = layers[i];
        const float* w  = (const float*)d_in[2 * l.wi];
        const float* bn = (const float*)d_in[2 * l.wi + 1];

        if (l.rb != prev_rb) {  // (re)build inverted rulebook
            const int* rin  = (const int*)d_in[l.rb];
            const int* rout = (const int*)d_in[l.rb + 1];
            int P  = in_sizes[l.rb] / l.K;
            int KP = l.K * P;
            hipMemsetAsync(inv, 0xFF, (size_t)l.nout * l.K * sizeof(int), stream);
            inv_build_kernel<<<dim3((KP + TPB - 1) / TPB), dim3(TPB), 0, stream>>>(
                rin, rout, inv, KP, P, l.K, l.nin);
            prev_rb = l.rb;
        }

        switch (i) {
        case 0:
            conv_kernel<4, 16, 64, 27><<<dim3((l.nout + 63) / 64), dim3(256), 0, stream>>>(
                cur, w, bn, inv, nxt, l.nout); break;
        case 1:
            conv_kernel<16, 16, 64, 27><<<dim3((l.nout + 63) / 64), dim3(256), 0, stream>>>(
                cur, w, bn, inv, nxt, l.nout); break;
        case 2:
            conv_kernel<16, 32, 64, 27><<<dim3((l.nout + 63) / 64), dim3(256), 0, stream>>>(
                cur, w, bn, inv, nxt, l.nout); break;
        case 3: case 4:
            conv_kernel<32, 32, 64, 27><<<dim3((l.nout + 63) / 64), dim3(256), 0, stream>>>(
                cur, w, bn, inv, nxt, l.nout); break;
        case 5:
            conv_kernel<32, 64, 64, 27><<<dim3((l.nout + 63) / 64), dim3(256), 0, stream>>>(
                cur, w, bn, inv, nxt, l.nout); break;
        case 6: case 7: case 8: case 9: case 10:
            conv_kernel<64, 64, 32, 27><<<dim3((l.nout + 31) / 32), dim3(256), 0, stream>>>(
                cur, w, bn, inv, nxt, l.nout); break;
        default:
            conv_kernel<64, 128, 32, 3><<<dim3((l.nout + 31) / 32), dim3(256), 0, stream>>>(
                cur, w, bn, inv, nxt, l.nout); break;
        }

        float* tmp = cur; cur = nxt; nxt = tmp;
    }

    // segment max -> d_out (zero-init; post-ReLU values are non-negative)
    hipMemsetAsync(d_out, 0, (size_t)out_size * sizeof(float), stream);
    const int* bidx = (const int*)d_in[42];
    long tot = (long)n5 * 128;
    segmax_kernel<<<dim3((unsigned)((tot + TPB - 1) / TPB)), dim3(TPB), 0, stream>>>(
        cur, bidx, (float*)d_out, tot, 128);
}